// Round 1
// baseline (672.482 us; speedup 1.0000x reference)
//
#include <hip/hip_runtime.h>
#include <hip/hip_bf16.h>
#include <math.h>

typedef unsigned short u16;
typedef unsigned int u32;
typedef __attribute__((ext_vector_type(8))) short short8;
typedef __attribute__((ext_vector_type(4))) float f32x4;

#define MFMA16(a,b,c) __builtin_amdgcn_mfma_f32_16x16x32_bf16((a),(b),(c),0,0,0)

// ---------- helpers ----------
__device__ __forceinline__ u16 f2bf(float f) {
  u32 u = __float_as_uint(f);
  u32 r = (u + 0x7FFFu + ((u >> 16) & 1u)) >> 16;
  return (u16)r;
}
__device__ __forceinline__ float bf2f(u16 h) { return __uint_as_float(((u32)h) << 16); }
__device__ __forceinline__ void f2hl(float f, u16& h, u16& l) {
  h = f2bf(f);
  l = f2bf(f - bf2f(h));
}
__device__ __forceinline__ float wsum64(float v) {
#pragma unroll
  for (int off = 32; off > 0; off >>= 1) v += __shfl_xor(v, off, 64);
  return v;
}
__device__ __forceinline__ short8 s8zero() {
  short8 v;
#pragma unroll
  for (int j = 0; j < 8; ++j) v[j] = 0;
  return v;
}

// ---------- kernel 0: cast inputs to bf16 (xb, Wcat[4224x1024], Wob) ----------
// chunks: xb 2097152, Wcat 1081344, Wob 262144  => total 3440640 = 13440*256
__global__ __launch_bounds__(256) void k_cast(
    const float* __restrict__ x, const float* __restrict__ Wq, const float* __restrict__ Wk,
    const float* __restrict__ Wv, const float* __restrict__ Wg, const float* __restrict__ lrw,
    const float* __restrict__ Wo, u16* __restrict__ xb, u16* __restrict__ Wcat, u16* __restrict__ Wob) {
  int c = blockIdx.x * 256 + threadIdx.x;
  float4 v = make_float4(0.f, 0.f, 0.f, 0.f);
  u16* dst;
  if (c < 2097152) {
    v = *(const float4*)(x + (size_t)c * 4);
    dst = xb + (size_t)c * 4;
  } else if (c < 2097152 + 1081344) {
    int c2 = c - 2097152;
    int base = c2 * 4;
    int nr = base >> 10, col = base & 1023;
    if (nr < 1024)      v = *(const float4*)(Wq  + (size_t)nr * 1024 + col);
    else if (nr < 2048) v = *(const float4*)(Wk  + (size_t)(nr - 1024) * 1024 + col);
    else if (nr < 3072) v = *(const float4*)(Wv  + (size_t)(nr - 2048) * 1024 + col);
    else if (nr < 4096) v = *(const float4*)(Wg  + (size_t)(nr - 3072) * 1024 + col);
    else if (nr < 4112) v = *(const float4*)(lrw + (size_t)(nr - 4096) * 1024 + col);
    // rows 4112..4223 stay zero (N padding)
    dst = Wcat + (size_t)base;
  } else {
    int c2 = c - (2097152 + 1081344);
    v = *(const float4*)(Wo + (size_t)c2 * 4);
    dst = Wob + (size_t)c2 * 4;
  }
  ushort4 o;
  o.x = f2bf(v.x); o.y = f2bf(v.y); o.z = f2bf(v.z); o.w = f2bf(v.w);
  *(ushort4*)dst = o;
}

// ---------- shared GEMM core: C[8192-tile x N-tile] = A @ B^T, bf16 MFMA ----------
// A: [M][1024] bf16 row-major, Bw: [N][1024] bf16 row-major (both K-contiguous, NT GEMM)
// 128x128 tile, BK=32, 4 waves each 64x64 (4x4 of 16x16 tiles)
__device__ __forceinline__ void gemm_core(const u16* __restrict__ A, const u16* __restrict__ Bw,
                                          int bm, int bn, u16* sA, u16* sB, f32x4 acc[4][4]) {
  int tid = threadIdx.x;
  int lane = tid & 63, wid = tid >> 6;
  int fr = lane & 15, qd = lane >> 4;
  int wm = (wid & 1) * 64, wn = (wid >> 1) * 64;
#pragma unroll
  for (int i = 0; i < 4; ++i)
#pragma unroll
    for (int j = 0; j < 4; ++j) {
      f32x4 zz = {0.f, 0.f, 0.f, 0.f};
      acc[i][j] = zz;
    }
  for (int k0 = 0; k0 < 1024; k0 += 32) {
    __syncthreads();
#pragma unroll
    for (int cc = 0; cc < 2; ++cc) {
      int ch = tid + cc * 256;
      int row = ch >> 2, kp = (ch & 3) << 3;
      *(uint4*)(sA + row * 40 + kp) = *(const uint4*)(A + (size_t)(bm * 128 + row) * 1024 + k0 + kp);
      *(uint4*)(sB + row * 40 + kp) = *(const uint4*)(Bw + (size_t)(bn * 128 + row) * 1024 + k0 + kp);
    }
    __syncthreads();
    short8 af[4], bfr[4];
#pragma unroll
    for (int i = 0; i < 4; ++i) af[i] = *(const short8*)(sA + (wm + i * 16 + fr) * 40 + qd * 8);
#pragma unroll
    for (int j = 0; j < 4; ++j) bfr[j] = *(const short8*)(sB + (wn + j * 16 + fr) * 40 + qd * 8);
#pragma unroll
    for (int i = 0; i < 4; ++i)
#pragma unroll
      for (int j = 0; j < 4; ++j) acc[i][j] = MFMA16(af[i], bfr[j], acc[i][j]);
  }
}

// ---------- kernel 1: fused QKV + gate + lr projection ----------
__global__ __launch_bounds__(256) void k_gemm1(
    const u16* __restrict__ A, const u16* __restrict__ Bw,
    float* __restrict__ Qf, float* __restrict__ Kf, float* __restrict__ Vf,
    u16* __restrict__ gateb, float* __restrict__ eta,
    const float* __restrict__ lr_b, const float* __restrict__ tio) {
  __shared__ __align__(16) u16 sA[128 * 40];
  __shared__ __align__(16) u16 sB[128 * 40];
  int bm = blockIdx.x & 63, bn = blockIdx.x >> 6;
  f32x4 acc[4][4];
  gemm_core(A, Bw, bm, bn, sA, sB, acc);
  int tid = threadIdx.x, lane = tid & 63, wid = tid >> 6;
  int fr = lane & 15, qd = lane >> 4;
  int wm = (wid & 1) * 64, wn = (wid >> 1) * 64;
#pragma unroll
  for (int i = 0; i < 4; ++i) {
    int gr0 = bm * 128 + wm + i * 16 + qd * 4;
#pragma unroll
    for (int j = 0; j < 4; ++j) {
      int gc = bn * 128 + wn + j * 16 + fr;
      if (gc < 3072) {
        int p = gc >> 10, rem = gc & 1023, hd = rem >> 6, dd = rem & 63;
        float* dst = (p == 0) ? Qf : ((p == 1) ? Kf : Vf);
#pragma unroll
        for (int r = 0; r < 4; ++r) {
          int gr = gr0 + r;
          int b_ = gr >> 11, s = gr & 2047;
          dst[(((size_t)(b_ * 16 + hd)) * 2048 + s) * 64 + dd] = acc[i][j][r];
        }
      } else if (gc < 4096) {
        int j2 = gc - 3072;
#pragma unroll
        for (int r = 0; r < 4; ++r) {
          int gr = gr0 + r;
          float vv = acc[i][j][r];
          float gl = 0.5f * vv * (1.0f + erff(vv * 0.70710678118654752f));  // exact gelu
          gateb[(size_t)gr * 1024 + j2] = f2bf(gl);
        }
      } else if (gc < 4112) {
        int hd = gc - 4096;
        float lb = lr_b[hd];
#pragma unroll
        for (int r = 0; r < 4; ++r) {
          int gr = gr0 + r;
          int b_ = gr >> 11, s = gr & 2047, m = s & 15;
          float lm = 1.0f / (1.0f + expf(-(acc[i][j][r] + lb)));
          float tok = fmaxf(1.0f / (float)(m + 1) + tio[m], 0.0f);
          eta[((size_t)(b_ * 16 + hd)) * 2048 + s] = tok * lm * 0.015625f;  // /D
        }
      }
    }
  }
}

// ---------- kernel 2: Phase A — sequential W/b trajectory per head ----------
// thread (wave w, lane e) holds W[d=16w+i][e] in registers; snapshots W_n transposed [e][d]
__global__ __launch_bounds__(256) void k_phaseA(
    const float* __restrict__ Kf, const float* __restrict__ Vf, const float* __restrict__ eta,
    const float* __restrict__ W_init, const float* __restrict__ b_init,
    const float* __restrict__ ttt_w, const float* __restrict__ ttt_b,
    float* __restrict__ Wseq, float* __restrict__ bseq) {
  __shared__ float part[4][4][64];  // [d-slice wave][batch][e]
  __shared__ float ush[4][64];      // [batch][e]
  int h = blockIdx.x;
  int tid = threadIdx.x, lane = tid & 63, w = tid >> 6;
  float Wreg[16];
#pragma unroll
  for (int i = 0; i < 16; ++i) Wreg[i] = W_init[(size_t)h * 4096 + (w * 16 + i) * 64 + lane];
  float bcur = b_init[h * 64 + lane];
  float g = ttt_w[h * 64 + lane], tb = ttt_b[h * 64 + lane];
  for (int n = 0; n < 128; ++n) {
    // snapshot W_n (pre-update), stored transposed: Wseq[h][n][e][d]
    float* wdst = Wseq + (((size_t)h * 128 + n) * 64 + lane) * 64 + w * 16;
#pragma unroll
    for (int i = 0; i < 16; i += 4) {
      float4 t4;
      t4.x = Wreg[i]; t4.y = Wreg[i + 1]; t4.z = Wreg[i + 2]; t4.w = Wreg[i + 3];
      *(float4*)(wdst + i) = t4;
    }
    if (w == 0) bseq[((size_t)h * 128 + n) * 64 + lane] = bcur;
    // last-row matvec partials for all 4 batches over this wave's d-slice
    const float* krow0 = Kf + (((size_t)(0 * 16 + h)) * 2048 + n * 16 + 15) * 64;
    const float* krow1 = Kf + (((size_t)(1 * 16 + h)) * 2048 + n * 16 + 15) * 64;
    const float* krow2 = Kf + (((size_t)(2 * 16 + h)) * 2048 + n * 16 + 15) * 64;
    const float* krow3 = Kf + (((size_t)(3 * 16 + h)) * 2048 + n * 16 + 15) * 64;
    float p0 = 0.f, p1 = 0.f, p2 = 0.f, p3 = 0.f;
#pragma unroll
    for (int i = 0; i < 16; ++i) {
      float wr = Wreg[i];
      p0 += krow0[w * 16 + i] * wr;
      p1 += krow1[w * 16 + i] * wr;
      p2 += krow2[w * 16 + i] * wr;
      p3 += krow3[w * 16 + i] * wr;
    }
    part[w][0][lane] = p0; part[w][1][lane] = p1;
    part[w][2][lane] = p2; part[w][3][lane] = p3;
    __syncthreads();
    // wave w does LN-vjp for batch w's last row
    const float* krw = Kf + (((size_t)(w * 16 + h)) * 2048 + n * 16 + 15) * 64;
    const float* vrw = Vf + (((size_t)(w * 16 + h)) * 2048 + n * 16 + 15) * 64;
    float z = bcur + part[0][w][lane] + part[1][w][lane] + part[2][w][lane] + part[3][w][lane];
    float m1 = wsum64(z) * 0.015625f;
    float xc = z - m1;
    float var = wsum64(xc * xc) * 0.015625f;
    float rstd = rsqrtf(var + 1e-5f);
    float kl = krw[lane], vl = vrw[lane];
    float ln = xc * rstd * g + tb;
    float go = ln - (vl - kl);
    float gxn = go * g;
    float sa = wsum64(gxn * xc);
    float sb_ = wsum64(gxn);
    float sc = wsum64(xc);
    float r3 = rstd * rstd * rstd;
    float gvar = -0.5f * sa * r3;
    float gmu = -sb_ * rstd + gvar * (-2.0f * sc) * 0.015625f;
    float gz = gxn * rstd + gvar * 2.0f * xc * 0.015625f + gmu * 0.015625f;
    float el = eta[((size_t)(w * 16 + h)) * 2048 + n * 16 + 15];
    ush[w][lane] = el * gz;
    __syncthreads();
    float u0 = ush[0][lane], u1 = ush[1][lane], u2 = ush[2][lane], u3 = ush[3][lane];
    bcur -= 0.25f * (u0 + u1 + u2 + u3);
#pragma unroll
    for (int i = 0; i < 16; ++i) {
      float a = krow0[w * 16 + i] * u0 + krow1[w * 16 + i] * u1 +
                krow2[w * 16 + i] * u2 + krow3[w * 16 + i] * u3;
      Wreg[i] -= 0.25f * a;
    }
  }
}

// ---------- kernel 3: Phase B — per-(minibatch, head) full outputs via MFMA hi/lo ----------
__global__ __launch_bounds__(256) void k_phaseB(
    const float* __restrict__ Qf, const float* __restrict__ Kf, const float* __restrict__ Vf,
    const float* __restrict__ eta, const float* __restrict__ Wseq, const float* __restrict__ bseq,
    const float* __restrict__ ttt_w, const float* __restrict__ ttt_b, float* __restrict__ yout) {
  __shared__ __align__(16) u16 WtH[64 * 72], WtL[64 * 72];   // W^T [e][d] hi/lo bf16, pad 72
  __shared__ __align__(16) u16 gzH[4][64 * 24], gzL[4][64 * 24];  // gZ^T [e][m] per wave
  __shared__ __align__(16) float At[4][16 * 20];             // Attn^T [n][m] per wave
  __shared__ float bsh[64];
  int bx = blockIdx.x;
  int n = bx & 127, h = bx >> 7;
  int tid = threadIdx.x, lane = tid & 63, wv = tid >> 6;  // wave = batch
  int fr = lane & 15, qd = lane >> 4;

  // stage W_n (already [e][d]) -> hi/lo bf16 LDS
  {
    int e = tid >> 2, d0 = (tid & 3) << 4;
    const float* src = Wseq + (((size_t)h * 128 + n) * 64 + e) * 64 + d0;
#pragma unroll
    for (int gsub = 0; gsub < 2; ++gsub) {
      u16 hb[8], lb_[8];
#pragma unroll
      for (int i = 0; i < 8; i += 4) {
        float4 v = *(const float4*)(src + gsub * 8 + i);
        f2hl(v.x, hb[i], lb_[i]);
        f2hl(v.y, hb[i + 1], lb_[i + 1]);
        f2hl(v.z, hb[i + 2], lb_[i + 2]);
        f2hl(v.w, hb[i + 3], lb_[i + 3]);
      }
      uint4 ph, pl;
      ph.x = hb[0] | ((u32)hb[1] << 16); ph.y = hb[2] | ((u32)hb[3] << 16);
      ph.z = hb[4] | ((u32)hb[5] << 16); ph.w = hb[6] | ((u32)hb[7] << 16);
      pl.x = lb_[0] | ((u32)lb_[1] << 16); pl.y = lb_[2] | ((u32)lb_[3] << 16);
      pl.z = lb_[4] | ((u32)lb_[5] << 16); pl.w = lb_[6] | ((u32)lb_[7] << 16);
      *(uint4*)(&WtH[e * 72 + d0 + gsub * 8]) = ph;
      *(uint4*)(&WtL[e * 72 + d0 + gsub * 8]) = pl;
    }
    if (tid < 64) bsh[tid] = bseq[((size_t)h * 128 + n) * 64 + tid];
  }
  __syncthreads();

  const size_t bh = (size_t)(wv * 16 + h);
  const float* Qp = Qf + (bh * 2048 + (size_t)n * 16) * 64;
  const float* Kp = Kf + (bh * 2048 + (size_t)n * 16) * 64;
  const float* Vp = Vf + (bh * 2048 + (size_t)n * 16) * 64;
  const float* ep = eta + bh * 2048 + n * 16;

  // Q/K A-operand fragments (also reused as B for Attn): [m=fr][k = s*32 + qd*8 + j]
  short8 qH[2], qL[2], kH[2], kL[2];
#pragma unroll
  for (int s = 0; s < 2; ++s) {
    const float* p1 = Qp + fr * 64 + s * 32 + qd * 8;
    const float* p2 = Kp + fr * 64 + s * 32 + qd * 8;
#pragma unroll
    for (int j = 0; j < 8; ++j) {
      u16 hb, lb_;
      f2hl(p1[j], hb, lb_); qH[s][j] = (short)hb; qL[s][j] = (short)lb_;
      f2hl(p2[j], hb, lb_); kH[s][j] = (short)hb; kL[s][j] = (short)lb_;
    }
  }

  // Z = K@W + b  (C-layout: row m = qd*4+r, col e = t*16+fr)
  f32x4 Zt[4];
#pragma unroll
  for (int t = 0; t < 4; ++t) {
    f32x4 a = {0.f, 0.f, 0.f, 0.f};
#pragma unroll
    for (int s = 0; s < 2; ++s) {
      short8 wH = *(const short8*)(&WtH[(t * 16 + fr) * 72 + s * 32 + qd * 8]);
      short8 wL = *(const short8*)(&WtL[(t * 16 + fr) * 72 + s * 32 + qd * 8]);
      a = MFMA16(kH[s], wH, a);
      a = MFMA16(kL[s], wH, a);
      a = MFMA16(kH[s], wL, a);
    }
    float bv = bsh[t * 16 + fr];
    a[0] += bv; a[1] += bv; a[2] += bv; a[3] += bv;
    Zt[t] = a;
  }
  // Attn = Q@K^T (16x16)
  f32x4 Atn = {0.f, 0.f, 0.f, 0.f};
#pragma unroll
  for (int s = 0; s < 2; ++s) {
    Atn = MFMA16(qH[s], kH[s], Atn);
    Atn = MFMA16(qL[s], kH[s], Atn);
    Atn = MFMA16(qH[s], kL[s], Atn);
  }

  // LN(Z) + vjp
  float gw[4], gb[4];
#pragma unroll
  for (int t = 0; t < 4; ++t) {
    gw[t] = ttt_w[h * 64 + t * 16 + fr];
    gb[t] = ttt_b[h * 64 + t * 16 + fr];
  }
  float s1[4], s2[4];
#pragma unroll
  for (int r = 0; r < 4; ++r) {
    float a0 = Zt[0][r], a1 = Zt[1][r], a2 = Zt[2][r], a3 = Zt[3][r];
    s1[r] = a0 + a1 + a2 + a3;
    s2[r] = a0 * a0 + a1 * a1 + a2 * a2 + a3 * a3;
  }
#pragma unroll
  for (int off = 1; off <= 8; off <<= 1) {
#pragma unroll
    for (int r = 0; r < 4; ++r) {
      s1[r] += __shfl_xor(s1[r], off, 64);
      s2[r] += __shfl_xor(s2[r], off, 64);
    }
  }
  float mu[4], rstd[4];
#pragma unroll
  for (int r = 0; r < 4; ++r) {
    mu[r] = s1[r] * 0.015625f;
    float var = s2[r] * 0.015625f - mu[r] * mu[r];
    rstd[r] = rsqrtf(var + 1e-5f);
  }
  float xc[4][4], gxn[4][4];
  float s3[4] = {0, 0, 0, 0}, s4[4] = {0, 0, 0, 0}, s5[4] = {0, 0, 0, 0};
#pragma unroll
  for (int t = 0; t < 4; ++t) {
#pragma unroll
    for (int r = 0; r < 4; ++r) {
      float z = Zt[t][r];
      float x = z - mu[r];
      xc[t][r] = x;
      float ln = x * rstd[r] * gw[t] + gb[t];
      float vV = Vp[(qd * 4 + r) * 64 + t * 16 + fr];
      float vK = Kp[(qd * 4 + r) * 64 + t * 16 + fr];
      float go = ln - (vV - vK);
      float gx = go * gw[t];
      gxn[t][r] = gx;
      s3[r] += gx * x;
      s4[r] += gx;
      s5[r] += x;
    }
  }
#pragma unroll
  for (int off = 1; off <= 8; off <<= 1) {
#pragma unroll
    for (int r = 0; r < 4; ++r) {
      s3[r] += __shfl_xor(s3[r], off, 64);
      s4[r] += __shfl_xor(s4[r], off, 64);
      s5[r] += __shfl_xor(s5[r], off, 64);
    }
  }
  float gvar[4], gmu[4];
#pragma unroll
  for (int r = 0; r < 4; ++r) {
    float r3 = rstd[r] * rstd[r] * rstd[r];
    gvar[r] = -0.5f * s3[r] * r3;
    gmu[r] = -s4[r] * rstd[r] + gvar[r] * (-2.0f * s5[r]) * 0.015625f;
  }
  // gZ -> LDS transposed [e][m], hi/lo bf16
#pragma unroll
  for (int t = 0; t < 4; ++t) {
    u16 hb[4], lb_[4];
#pragma unroll
    for (int r = 0; r < 4; ++r) {
      float gz = gxn[t][r] * rstd[r] + gvar[r] * 2.0f * xc[t][r] * 0.015625f + gmu[r] * 0.015625f;
      f2hl(gz, hb[r], lb_[r]);
    }
    uint2 ph, pl;
    ph.x = hb[0] | ((u32)hb[1] << 16); ph.y = hb[2] | ((u32)hb[3] << 16);
    pl.x = lb_[0] | ((u32)lb_[1] << 16); pl.y = lb_[2] | ((u32)lb_[3] << 16);
    *(uint2*)(&gzH[wv][(t * 16 + fr) * 24 + qd * 4]) = ph;
    *(uint2*)(&gzL[wv][(t * 16 + fr) * 24 + qd * 4]) = pl;
  }
  // Attn -> LDS transposed At[n][m]
  *(f32x4*)(&At[wv][fr * 20 + qd * 4]) = Atn;

  // Combined A = em[m]*(1 + tril(Attn))[m][n] for n<=m  (covers tril1 + Attn terms)
  float em = ep[fr];
  short8 aH = s8zero(), aL = s8zero();
  if (qd < 2) {
#pragma unroll
    for (int j = 0; j < 8; ++j) {
      int nn = qd * 8 + j;
      float av = 0.0f;
      if (nn <= fr) av = em * (1.0f + At[wv][nn * 20 + fr]);
      u16 hb, lb_;
      f2hl(av, hb, lb_);
      aH[j] = (short)hb;
      aL[j] = (short)lb_;
    }
  }
  // Zb = Q@W + b - Acomb@gZ
  f32x4 Ob[4];
#pragma unroll
  for (int t = 0; t < 4; ++t) {
    f32x4 a = {0.f, 0.f, 0.f, 0.f};
#pragma unroll
    for (int s = 0; s < 2; ++s) {
      short8 wH = *(const short8*)(&WtH[(t * 16 + fr) * 72 + s * 32 + qd * 8]);
      short8 wL = *(const short8*)(&WtL[(t * 16 + fr) * 72 + s * 32 + qd * 8]);
      a = MFMA16(qH[s], wH, a);
      a = MFMA16(qL[s], wH, a);
      a = MFMA16(qH[s], wL, a);
    }
    short8 gH = s8zero(), gL = s8zero();
    if (qd < 2) {
      gH = *(const short8*)(&gzH[wv][(t * 16 + fr) * 24 + qd * 8]);
      gL = *(const short8*)(&gzL[wv][(t * 16 + fr) * 24 + qd * 8]);
    }
    f32x4 c = {0.f, 0.f, 0.f, 0.f};
    c = MFMA16(aH, gH, c);
    c = MFMA16(aL, gH, c);
    c = MFMA16(aH, gL, c);
    float bv = bsh[t * 16 + fr];
#pragma unroll
    for (int r = 0; r < 4; ++r) Ob[t][r] = a[r] - c[r] + bv;
  }
  // out = Q + LN(Zb)
#pragma unroll
  for (int r = 0; r < 4; ++r) {
    float a0 = Ob[0][r], a1 = Ob[1][r], a2 = Ob[2][r], a3 = Ob[3][r];
    s1[r] = a0 + a1 + a2 + a3;
    s2[r] = a0 * a0 + a1 * a1 + a2 * a2 + a3 * a3;
  }
#pragma unroll
  for (int off = 1; off <= 8; off <<= 1) {
#pragma unroll
    for (int r = 0; r < 4; ++r) {
      s1[r] += __shfl_xor(s1[r], off, 64);
      s2[r] += __shfl_xor(s2[r], off, 64);
    }
  }
#pragma unroll
  for (int r = 0; r < 4; ++r) {
    mu[r] = s1[r] * 0.015625f;
    float var = s2[r] * 0.015625f - mu[r] * mu[r];
    rstd[r] = rsqrtf(var + 1e-5f);
  }
#pragma unroll
  for (int t = 0; t < 4; ++t) {
#pragma unroll
    for (int r = 0; r < 4; ++r) {
      float ln = (Ob[t][r] - mu[r]) * rstd[r] * gw[t] + gb[t];
      float qv = Qp[(qd * 4 + r) * 64 + t * 16 + fr];
      yout[((size_t)wv * 2048 + n * 16 + qd * 4 + r) * 1024 + h * 64 + t * 16 + fr] = qv + ln;
    }
  }
}

// ---------- kernel 4: post-LN + gate -> zb (bf16) ----------
__global__ __launch_bounds__(256) void k_postln(
    const float* __restrict__ yf, const u16* __restrict__ gateb,
    const float* __restrict__ post_w, const float* __restrict__ post_b, u16* __restrict__ zb) {
  __shared__ float red[8];
  int row = blockIdx.x, tid = threadIdx.x;
  int lane = tid & 63, wid = tid >> 6;
  const float* yr = yf + (size_t)row * 1024;
  float4 v = *(const float4*)(yr + tid * 4);
  float s1 = v.x + v.y + v.z + v.w;
  float s2 = v.x * v.x + v.y * v.y + v.z * v.z + v.w * v.w;
  s1 = wsum64(s1);
  s2 = wsum64(s2);
  if (lane == 0) { red[wid] = s1; red[4 + wid] = s2; }
  __syncthreads();
  s1 = red[0] + red[1] + red[2] + red[3];
  s2 = red[4] + red[5] + red[6] + red[7];
  float mu = s1 * (1.0f / 1024.0f);
  float var = s2 * (1.0f / 1024.0f) - mu * mu;
  float rstd = rsqrtf(var + 1e-5f);
  float vals[4] = {v.x, v.y, v.z, v.w};
  u16 ov[4];
#pragma unroll
  for (int i = 0; i < 4; ++i) {
    int cc = tid * 4 + i;
    float yn = (vals[i] - mu) * rstd * post_w[cc] + post_b[cc];
    float gt = bf2f(gateb[(size_t)row * 1024 + cc]);
    ov[i] = f2bf(gt * yn);
  }
  ushort4 o;
  o.x = ov[0]; o.y = ov[1]; o.z = ov[2]; o.w = ov[3];
  *(ushort4*)(zb + (size_t)row * 1024 + tid * 4) = o;
}

// ---------- kernel 5: output GEMM ----------
__global__ __launch_bounds__(256) void k_gemm2(const u16* __restrict__ A, const u16* __restrict__ Bw,
                                               float* __restrict__ Out) {
  __shared__ __align__(16) u16 sA[128 * 40];
  __shared__ __align__(16) u16 sB[128 * 40];
  int bm = blockIdx.x & 63, bn = blockIdx.x >> 6;
  f32x4 acc[4][4];
  gemm_core(A, Bw, bm, bn, sA, sB, acc);
  int tid = threadIdx.x, lane = tid & 63, wid = tid >> 6;
  int fr = lane & 15, qd = lane >> 4;
  int wm = (wid & 1) * 64, wn = (wid >> 1) * 64;
#pragma unroll
  for (int i = 0; i < 4; ++i) {
    int gr0 = bm * 128 + wm + i * 16 + qd * 4;
#pragma unroll
    for (int j = 0; j < 4; ++j) {
      int gc = bn * 128 + wn + j * 16 + fr;
#pragma unroll
      for (int r = 0; r < 4; ++r) Out[(size_t)(gr0 + r) * 1024 + gc] = acc[i][j][r];
    }
  }
}

// ---------- workspace layout (bytes) ----------
#define OFF_XB    ((size_t)0)          // 8192*1024 bf16      = 16777216
#define OFF_WCAT  ((size_t)16777216)   // 4224*1024 bf16      =  8650752
#define OFF_WOB   ((size_t)25427968)   // 1024*1024 bf16      =  2097152
#define OFF_Q     ((size_t)27525120)   // 4*16*2048*64 f32    = 33554432
#define OFF_K     ((size_t)61079552)
#define OFF_V     ((size_t)94633984)
#define OFF_GATE  ((size_t)128188416)  // 8192*1024 bf16
#define OFF_ETA   ((size_t)144965632)  // 4*16*2048 f32
#define OFF_WSEQ  ((size_t)145489920)  // 16*128*64*64 f32
#define OFF_BSEQ  ((size_t)179044352)  // 16*128*64 f32
#define OFF_Y     ((size_t)179568640)  // 8192*1024 f32
#define OFF_ZB    ((size_t)213123072)  // 8192*1024 bf16  (end = 229900288)

extern "C" void kernel_launch(void* const* d_in, const int* in_sizes, int n_in,
                              void* d_out, int out_size, void* d_ws, size_t ws_size,
                              hipStream_t stream) {
  const float* x    = (const float*)d_in[0];
  const float* Wq   = (const float*)d_in[1];
  const float* Wk   = (const float*)d_in[2];
  const float* Wv   = (const float*)d_in[3];
  const float* Wini = (const float*)d_in[4];
  const float* bini = (const float*)d_in[5];
  const float* ttw  = (const float*)d_in[6];
  const float* ttb  = (const float*)d_in[7];
  const float* pw   = (const float*)d_in[8];
  const float* pb   = (const float*)d_in[9];
  const float* lrw  = (const float*)d_in[10];
  const float* lrb  = (const float*)d_in[11];
  const float* tio  = (const float*)d_in[12];
  const float* Wg   = (const float*)d_in[13];
  const float* Wo   = (const float*)d_in[14];
  (void)in_sizes; (void)n_in; (void)out_size; (void)ws_size;
  float* out = (float*)d_out;
  char* ws = (char*)d_ws;
  u16* xb    = (u16*)(ws + OFF_XB);
  u16* Wcat  = (u16*)(ws + OFF_WCAT);
  u16* Wob   = (u16*)(ws + OFF_WOB);
  float* Qf  = (float*)(ws + OFF_Q);
  float* Kf  = (float*)(ws + OFF_K);
  float* Vf  = (float*)(ws + OFF_V);
  u16* gateb = (u16*)(ws + OFF_GATE);
  float* eta = (float*)(ws + OFF_ETA);
  float* Wsq = (float*)(ws + OFF_WSEQ);
  float* bsq = (float*)(ws + OFF_BSEQ);
  float* yf  = (float*)(ws + OFF_Y);
  u16* zbuf  = (u16*)(ws + OFF_ZB);

  hipLaunchKernelGGL(k_cast, dim3(13440), dim3(256), 0, stream, x, Wq, Wk, Wv, Wg, lrw, Wo, xb, Wcat, Wob);
  hipLaunchKernelGGL(k_gemm1, dim3(64 * 33), dim3(256), 0, stream, xb, Wcat, Qf, Kf, Vf, gateb, eta, lrb, tio);
  hipLaunchKernelGGL(k_phaseA, dim3(16), dim3(256), 0, stream, Kf, Vf, eta, Wini, bini, ttw, ttb, Wsq, bsq);
  hipLaunchKernelGGL(k_phaseB, dim3(2048), dim3(256), 0, stream, Qf, Kf, Vf, eta, Wsq, bsq, ttw, ttb, yf);
  hipLaunchKernelGGL(k_postln, dim3(8192), dim3(256), 0, stream, yf, gateb, pw, pb, zbuf);
  hipLaunchKernelGGL(k_gemm2, dim3(64 * 8), dim3(256), 0, stream, zbuf, Wob, out);
}

// Round 2
// 594.407 us; speedup vs baseline: 1.1313x; 1.1313x over previous
//
#include <hip/hip_runtime.h>
#include <hip/hip_bf16.h>
#include <math.h>

typedef unsigned short u16;
typedef unsigned int u32;
typedef __attribute__((ext_vector_type(8))) short short8;
typedef __attribute__((ext_vector_type(4))) float f32x4;

#define MFMA16(a,b,c) __builtin_amdgcn_mfma_f32_16x16x32_bf16((a),(b),(c),0,0,0)

// ---------- helpers ----------
__device__ __forceinline__ u16 f2bf(float f) {
  u32 u = __float_as_uint(f);
  u32 r = (u + 0x7FFFu + ((u >> 16) & 1u)) >> 16;
  return (u16)r;
}
__device__ __forceinline__ float bf2f(u16 h) { return __uint_as_float(((u32)h) << 16); }
__device__ __forceinline__ void f2hl(float f, u16& h, u16& l) {
  h = f2bf(f);
  l = f2bf(f - bf2f(h));
}
__device__ __forceinline__ float wsum64(float v) {
#pragma unroll
  for (int off = 32; off > 0; off >>= 1) v += __shfl_xor(v, off, 64);
  return v;
}
// DPP wave-64 sum: 6 v_add links (row_shr 1/2/4/8, bcast15, bcast31), total in
// lane 63, broadcast via readlane -> SGPR. ~10x cheaper than ds_swizzle chains.
__device__ __forceinline__ float wred64(float v) {
  v += __int_as_float(__builtin_amdgcn_update_dpp(0, __float_as_int(v), 0x111, 0xf, 0xf, true));
  v += __int_as_float(__builtin_amdgcn_update_dpp(0, __float_as_int(v), 0x112, 0xf, 0xf, true));
  v += __int_as_float(__builtin_amdgcn_update_dpp(0, __float_as_int(v), 0x114, 0xf, 0xf, true));
  v += __int_as_float(__builtin_amdgcn_update_dpp(0, __float_as_int(v), 0x118, 0xf, 0xf, true));
  v += __int_as_float(__builtin_amdgcn_update_dpp(0, __float_as_int(v), 0x142, 0xa, 0xf, true));
  v += __int_as_float(__builtin_amdgcn_update_dpp(0, __float_as_int(v), 0x143, 0xc, 0xf, true));
  return __int_as_float(__builtin_amdgcn_readlane(__float_as_int(v), 63));
}
__device__ __forceinline__ short8 s8zero() {
  short8 v;
#pragma unroll
  for (int j = 0; j < 8; ++j) v[j] = 0;
  return v;
}

// ---------- kernel 0: cast inputs to bf16 (xb, Wcat[4224x1024], Wob) ----------
// chunks: xb 2097152, Wcat 1081344, Wob 262144  => total 3440640 = 13440*256
__global__ __launch_bounds__(256) void k_cast(
    const float* __restrict__ x, const float* __restrict__ Wq, const float* __restrict__ Wk,
    const float* __restrict__ Wv, const float* __restrict__ Wg, const float* __restrict__ lrw,
    const float* __restrict__ Wo, u16* __restrict__ xb, u16* __restrict__ Wcat, u16* __restrict__ Wob) {
  int c = blockIdx.x * 256 + threadIdx.x;
  float4 v = make_float4(0.f, 0.f, 0.f, 0.f);
  u16* dst;
  if (c < 2097152) {
    v = *(const float4*)(x + (size_t)c * 4);
    dst = xb + (size_t)c * 4;
  } else if (c < 2097152 + 1081344) {
    int c2 = c - 2097152;
    int base = c2 * 4;
    int nr = base >> 10, col = base & 1023;
    if (nr < 1024)      v = *(const float4*)(Wq  + (size_t)nr * 1024 + col);
    else if (nr < 2048) v = *(const float4*)(Wk  + (size_t)(nr - 1024) * 1024 + col);
    else if (nr < 3072) v = *(const float4*)(Wv  + (size_t)(nr - 2048) * 1024 + col);
    else if (nr < 4096) v = *(const float4*)(Wg  + (size_t)(nr - 3072) * 1024 + col);
    else if (nr < 4112) v = *(const float4*)(lrw + (size_t)(nr - 4096) * 1024 + col);
    // rows 4112..4223 stay zero (N padding)
    dst = Wcat + (size_t)base;
  } else {
    int c2 = c - (2097152 + 1081344);
    v = *(const float4*)(Wo + (size_t)c2 * 4);
    dst = Wob + (size_t)c2 * 4;
  }
  ushort4 o;
  o.x = f2bf(v.x); o.y = f2bf(v.y); o.z = f2bf(v.z); o.w = f2bf(v.w);
  *(ushort4*)dst = o;
}

// ---------- shared GEMM core: C[8192-tile x N-tile] = A @ B^T, bf16 MFMA ----------
// A: [M][1024] bf16 row-major, Bw: [N][1024] bf16 row-major (both K-contiguous, NT GEMM)
// 128x128 tile, BK=32, 4 waves each 64x64 (4x4 of 16x16 tiles)
__device__ __forceinline__ void gemm_core(const u16* __restrict__ A, const u16* __restrict__ Bw,
                                          int bm, int bn, u16* sA, u16* sB, f32x4 acc[4][4]) {
  int tid = threadIdx.x;
  int lane = tid & 63, wid = tid >> 6;
  int fr = lane & 15, qd = lane >> 4;
  int wm = (wid & 1) * 64, wn = (wid >> 1) * 64;
#pragma unroll
  for (int i = 0; i < 4; ++i)
#pragma unroll
    for (int j = 0; j < 4; ++j) {
      f32x4 zz = {0.f, 0.f, 0.f, 0.f};
      acc[i][j] = zz;
    }
  for (int k0 = 0; k0 < 1024; k0 += 32) {
    __syncthreads();
#pragma unroll
    for (int cc = 0; cc < 2; ++cc) {
      int ch = tid + cc * 256;
      int row = ch >> 2, kp = (ch & 3) << 3;
      *(uint4*)(sA + row * 40 + kp) = *(const uint4*)(A + (size_t)(bm * 128 + row) * 1024 + k0 + kp);
      *(uint4*)(sB + row * 40 + kp) = *(const uint4*)(Bw + (size_t)(bn * 128 + row) * 1024 + k0 + kp);
    }
    __syncthreads();
    short8 af[4], bfr[4];
#pragma unroll
    for (int i = 0; i < 4; ++i) af[i] = *(const short8*)(sA + (wm + i * 16 + fr) * 40 + qd * 8);
#pragma unroll
    for (int j = 0; j < 4; ++j) bfr[j] = *(const short8*)(sB + (wn + j * 16 + fr) * 40 + qd * 8);
#pragma unroll
    for (int i = 0; i < 4; ++i)
#pragma unroll
      for (int j = 0; j < 4; ++j) acc[i][j] = MFMA16(af[i], bfr[j], acc[i][j]);
  }
}

// ---------- kernel 1: fused QKV + gate + lr projection ----------
__global__ __launch_bounds__(256) void k_gemm1(
    const u16* __restrict__ A, const u16* __restrict__ Bw,
    float* __restrict__ Qf, float* __restrict__ Kf, float* __restrict__ Vf,
    u16* __restrict__ gateb, float* __restrict__ eta,
    const float* __restrict__ lr_b, const float* __restrict__ tio) {
  __shared__ __align__(16) u16 sA[128 * 40];
  __shared__ __align__(16) u16 sB[128 * 40];
  int bm = blockIdx.x & 63, bn = blockIdx.x >> 6;
  f32x4 acc[4][4];
  gemm_core(A, Bw, bm, bn, sA, sB, acc);
  int tid = threadIdx.x, lane = tid & 63, wid = tid >> 6;
  int fr = lane & 15, qd = lane >> 4;
  int wm = (wid & 1) * 64, wn = (wid >> 1) * 64;
#pragma unroll
  for (int i = 0; i < 4; ++i) {
    int gr0 = bm * 128 + wm + i * 16 + qd * 4;
#pragma unroll
    for (int j = 0; j < 4; ++j) {
      int gc = bn * 128 + wn + j * 16 + fr;
      if (gc < 3072) {
        int p = gc >> 10, rem = gc & 1023, hd = rem >> 6, dd = rem & 63;
        float* dst = (p == 0) ? Qf : ((p == 1) ? Kf : Vf);
#pragma unroll
        for (int r = 0; r < 4; ++r) {
          int gr = gr0 + r;
          int b_ = gr >> 11, s = gr & 2047;
          dst[(((size_t)(b_ * 16 + hd)) * 2048 + s) * 64 + dd] = acc[i][j][r];
        }
      } else if (gc < 4096) {
        int j2 = gc - 3072;
#pragma unroll
        for (int r = 0; r < 4; ++r) {
          int gr = gr0 + r;
          float vv = acc[i][j][r];
          float gl = 0.5f * vv * (1.0f + erff(vv * 0.70710678118654752f));  // exact gelu
          gateb[(size_t)gr * 1024 + j2] = f2bf(gl);
        }
      } else if (gc < 4112) {
        int hd = gc - 4096;
        float lb = lr_b[hd];
#pragma unroll
        for (int r = 0; r < 4; ++r) {
          int gr = gr0 + r;
          int b_ = gr >> 11, s = gr & 2047, m = s & 15;
          float lm = 1.0f / (1.0f + expf(-(acc[i][j][r] + lb)));
          float tok = fmaxf(1.0f / (float)(m + 1) + tio[m], 0.0f);
          eta[((size_t)(b_ * 16 + hd)) * 2048 + s] = tok * lm * 0.015625f;  // /D
        }
      }
    }
  }
}

// ---------- kernel 2: Phase A — sequential W/b trajectory per head ----------
// thread (wave w, lane e) holds W[d=16w+i][e] in registers; snapshots W_n transposed [e][d]
// R2: wave-uniform (readfirstlane) indices so K-row reads become s_loads; DPP
// reductions instead of ds_swizzle; snapshot stores issued right after barrier1
// so the LN section overlaps the vmcnt drain before barrier2.
__global__ __launch_bounds__(256) void k_phaseA(
    const float* __restrict__ Kf, const float* __restrict__ Vf, const float* __restrict__ eta,
    const float* __restrict__ W_init, const float* __restrict__ b_init,
    const float* __restrict__ ttt_w, const float* __restrict__ ttt_b,
    float* __restrict__ Wseq, float* __restrict__ bseq) {
  __shared__ float part[4][4][64];  // [d-slice wave][batch][e]
  __shared__ float ush[4][64];      // [batch][e]
  int h = blockIdx.x;
  int tid = threadIdx.x, lane = tid & 63;
  int wu = __builtin_amdgcn_readfirstlane(tid >> 6);  // provably wave-uniform wave id
  float Wreg[16];
#pragma unroll
  for (int i = 0; i < 16; ++i) Wreg[i] = W_init[(size_t)h * 4096 + (wu * 16 + i) * 64 + lane];
  float bcur = b_init[h * 64 + lane];
  float g = ttt_w[h * 64 + lane], tb = ttt_b[h * 64 + lane];
  // uniform K-row bases (batch 0..3), last row (m=15) of each minibatch
  const float* kb0 = Kf + (((size_t)(0 * 16 + h)) * 2048 + 15) * 64;
  const float* kb1 = Kf + (((size_t)(1 * 16 + h)) * 2048 + 15) * 64;
  const float* kb2 = Kf + (((size_t)(2 * 16 + h)) * 2048 + 15) * 64;
  const float* kb3 = Kf + (((size_t)(3 * 16 + h)) * 2048 + 15) * 64;
  for (int n = 0; n < 128; ++n) {
    const float* kr0 = kb0 + (size_t)n * 1024;  // uniform -> s_load
    const float* kr1 = kb1 + (size_t)n * 1024;
    const float* kr2 = kb2 + (size_t)n * 1024;
    const float* kr3 = kb3 + (size_t)n * 1024;
    // matvec partials for all 4 batches over this wave's d-slice (uniform k as SGPR operand)
    float p0 = 0.f, p1 = 0.f, p2 = 0.f, p3 = 0.f;
#pragma unroll
    for (int i = 0; i < 16; ++i) {
      float wr = Wreg[i];
      p0 += kr0[wu * 16 + i] * wr;
      p1 += kr1[wu * 16 + i] * wr;
      p2 += kr2[wu * 16 + i] * wr;
      p3 += kr3[wu * 16 + i] * wr;
    }
    part[wu][0][lane] = p0; part[wu][1][lane] = p1;
    part[wu][2][lane] = p2; part[wu][3][lane] = p3;
    __syncthreads();
    // snapshot W_n / b_n AFTER barrier1: drain overlaps the LN section below.
    // layout unchanged: Wseq[h][n][e][d]
    {
      float* wdst = Wseq + (((size_t)h * 128 + n) * 64 + lane) * 64 + wu * 16;
#pragma unroll
      for (int i = 0; i < 16; i += 4) {
        float4 t4;
        t4.x = Wreg[i]; t4.y = Wreg[i + 1]; t4.z = Wreg[i + 2]; t4.w = Wreg[i + 3];
        *(float4*)(wdst + i) = t4;
      }
      if (wu == 0) bseq[((size_t)h * 128 + n) * 64 + lane] = bcur;
    }
    // wave wu does LN-vjp for batch wu's last row
    const float* krw = Kf + (((size_t)(wu * 16 + h)) * 2048 + n * 16 + 15) * 64;
    const float* vrw = Vf + (((size_t)(wu * 16 + h)) * 2048 + n * 16 + 15) * 64;
    float kl = krw[lane], vl = vrw[lane];  // coalesced vector loads
    float z = bcur + part[0][wu][lane] + part[1][wu][lane] + part[2][wu][lane] + part[3][wu][lane];
    float m1 = wred64(z) * 0.015625f;
    float xc = z - m1;
    float var = wred64(xc * xc) * 0.015625f;
    float rstd = rsqrtf(var + 1e-5f);
    float ln = xc * rstd * g + tb;
    float go = ln - (vl - kl);
    float gxn = go * g;
    float sa = wred64(gxn * xc);
    float sb_ = wred64(gxn);
    float sc = wred64(xc);
    float r3 = rstd * rstd * rstd;
    float gvar = -0.5f * sa * r3;
    float gmu = -sb_ * rstd + gvar * (-2.0f * sc) * 0.015625f;
    float gz = gxn * rstd + gvar * 2.0f * xc * 0.015625f + gmu * 0.015625f;
    float el = eta[((size_t)(wu * 16 + h)) * 2048 + n * 16 + 15];  // uniform -> s_load
    ush[wu][lane] = el * gz;
    __syncthreads();
    float u0 = ush[0][lane], u1 = ush[1][lane], u2 = ush[2][lane], u3 = ush[3][lane];
    bcur -= 0.25f * (u0 + u1 + u2 + u3);
#pragma unroll
    for (int i = 0; i < 16; ++i) {
      float a = kr0[wu * 16 + i] * u0 + kr1[wu * 16 + i] * u1 +
                kr2[wu * 16 + i] * u2 + kr3[wu * 16 + i] * u3;
      Wreg[i] -= 0.25f * a;
    }
  }
}

// ---------- kernel 3: Phase B — per-(minibatch, head) full outputs via MFMA hi/lo ----------
__global__ __launch_bounds__(256) void k_phaseB(
    const float* __restrict__ Qf, const float* __restrict__ Kf, const float* __restrict__ Vf,
    const float* __restrict__ eta, const float* __restrict__ Wseq, const float* __restrict__ bseq,
    const float* __restrict__ ttt_w, const float* __restrict__ ttt_b, float* __restrict__ yout) {
  __shared__ __align__(16) u16 WtH[64 * 72], WtL[64 * 72];   // W^T [e][d] hi/lo bf16, pad 72
  __shared__ __align__(16) u16 gzH[4][64 * 24], gzL[4][64 * 24];  // gZ^T [e][m] per wave
  __shared__ __align__(16) float At[4][16 * 20];             // Attn^T [n][m] per wave
  __shared__ float bsh[64];
  int bx = blockIdx.x;
  int n = bx & 127, h = bx >> 7;
  int tid = threadIdx.x, lane = tid & 63, wv = tid >> 6;  // wave = batch
  int fr = lane & 15, qd = lane >> 4;

  // stage W_n (already [e][d]) -> hi/lo bf16 LDS
  {
    int e = tid >> 2, d0 = (tid & 3) << 4;
    const float* src = Wseq + (((size_t)h * 128 + n) * 64 + e) * 64 + d0;
#pragma unroll
    for (int gsub = 0; gsub < 2; ++gsub) {
      u16 hb[8], lb_[8];
#pragma unroll
      for (int i = 0; i < 8; i += 4) {
        float4 v = *(const float4*)(src + gsub * 8 + i);
        f2hl(v.x, hb[i], lb_[i]);
        f2hl(v.y, hb[i + 1], lb_[i + 1]);
        f2hl(v.z, hb[i + 2], lb_[i + 2]);
        f2hl(v.w, hb[i + 3], lb_[i + 3]);
      }
      uint4 ph, pl;
      ph.x = hb[0] | ((u32)hb[1] << 16); ph.y = hb[2] | ((u32)hb[3] << 16);
      ph.z = hb[4] | ((u32)hb[5] << 16); ph.w = hb[6] | ((u32)hb[7] << 16);
      pl.x = lb_[0] | ((u32)lb_[1] << 16); pl.y = lb_[2] | ((u32)lb_[3] << 16);
      pl.z = lb_[4] | ((u32)lb_[5] << 16); pl.w = lb_[6] | ((u32)lb_[7] << 16);
      *(uint4*)(&WtH[e * 72 + d0 + gsub * 8]) = ph;
      *(uint4*)(&WtL[e * 72 + d0 + gsub * 8]) = pl;
    }
    if (tid < 64) bsh[tid] = bseq[((size_t)h * 128 + n) * 64 + tid];
  }
  __syncthreads();

  const size_t bh = (size_t)(wv * 16 + h);
  const float* Qp = Qf + (bh * 2048 + (size_t)n * 16) * 64;
  const float* Kp = Kf + (bh * 2048 + (size_t)n * 16) * 64;
  const float* Vp = Vf + (bh * 2048 + (size_t)n * 16) * 64;
  const float* ep = eta + bh * 2048 + n * 16;

  // Q/K A-operand fragments (also reused as B for Attn): [m=fr][k = s*32 + qd*8 + j]
  short8 qH[2], qL[2], kH[2], kL[2];
#pragma unroll
  for (int s = 0; s < 2; ++s) {
    const float* p1 = Qp + fr * 64 + s * 32 + qd * 8;
    const float* p2 = Kp + fr * 64 + s * 32 + qd * 8;
#pragma unroll
    for (int j = 0; j < 8; ++j) {
      u16 hb, lb_;
      f2hl(p1[j], hb, lb_); qH[s][j] = (short)hb; qL[s][j] = (short)lb_;
      f2hl(p2[j], hb, lb_); kH[s][j] = (short)hb; kL[s][j] = (short)lb_;
    }
  }

  // Z = K@W + b  (C-layout: row m = qd*4+r, col e = t*16+fr)
  f32x4 Zt[4];
#pragma unroll
  for (int t = 0; t < 4; ++t) {
    f32x4 a = {0.f, 0.f, 0.f, 0.f};
#pragma unroll
    for (int s = 0; s < 2; ++s) {
      short8 wH = *(const short8*)(&WtH[(t * 16 + fr) * 72 + s * 32 + qd * 8]);
      short8 wL = *(const short8*)(&WtL[(t * 16 + fr) * 72 + s * 32 + qd * 8]);
      a = MFMA16(kH[s], wH, a);
      a = MFMA16(kL[s], wH, a);
      a = MFMA16(kH[s], wL, a);
    }
    float bv = bsh[t * 16 + fr];
    a[0] += bv; a[1] += bv; a[2] += bv; a[3] += bv;
    Zt[t] = a;
  }
  // Attn = Q@K^T (16x16)
  f32x4 Atn = {0.f, 0.f, 0.f, 0.f};
#pragma unroll
  for (int s = 0; s < 2; ++s) {
    Atn = MFMA16(qH[s], kH[s], Atn);
    Atn = MFMA16(qL[s], kH[s], Atn);
    Atn = MFMA16(qH[s], kL[s], Atn);
  }

  // LN(Z) + vjp
  float gw[4], gb[4];
#pragma unroll
  for (int t = 0; t < 4; ++t) {
    gw[t] = ttt_w[h * 64 + t * 16 + fr];
    gb[t] = ttt_b[h * 64 + t * 16 + fr];
  }
  float s1[4], s2[4];
#pragma unroll
  for (int r = 0; r < 4; ++r) {
    float a0 = Zt[0][r], a1 = Zt[1][r], a2 = Zt[2][r], a3 = Zt[3][r];
    s1[r] = a0 + a1 + a2 + a3;
    s2[r] = a0 * a0 + a1 * a1 + a2 * a2 + a3 * a3;
  }
#pragma unroll
  for (int off = 1; off <= 8; off <<= 1) {
#pragma unroll
    for (int r = 0; r < 4; ++r) {
      s1[r] += __shfl_xor(s1[r], off, 64);
      s2[r] += __shfl_xor(s2[r], off, 64);
    }
  }
  float mu[4], rstd[4];
#pragma unroll
  for (int r = 0; r < 4; ++r) {
    mu[r] = s1[r] * 0.015625f;
    float var = s2[r] * 0.015625f - mu[r] * mu[r];
    rstd[r] = rsqrtf(var + 1e-5f);
  }
  float xc[4][4], gxn[4][4];
  float s3[4] = {0, 0, 0, 0}, s4[4] = {0, 0, 0, 0}, s5[4] = {0, 0, 0, 0};
#pragma unroll
  for (int t = 0; t < 4; ++t) {
#pragma unroll
    for (int r = 0; r < 4; ++r) {
      float z = Zt[t][r];
      float x = z - mu[r];
      xc[t][r] = x;
      float ln = x * rstd[r] * gw[t] + gb[t];
      float vV = Vp[(qd * 4 + r) * 64 + t * 16 + fr];
      float vK = Kp[(qd * 4 + r) * 64 + t * 16 + fr];
      float go = ln - (vV - vK);
      float gx = go * gw[t];
      gxn[t][r] = gx;
      s3[r] += gx * x;
      s4[r] += gx;
      s5[r] += x;
    }
  }
#pragma unroll
  for (int off = 1; off <= 8; off <<= 1) {
#pragma unroll
    for (int r = 0; r < 4; ++r) {
      s3[r] += __shfl_xor(s3[r], off, 64);
      s4[r] += __shfl_xor(s4[r], off, 64);
      s5[r] += __shfl_xor(s5[r], off, 64);
    }
  }
  float gvar[4], gmu[4];
#pragma unroll
  for (int r = 0; r < 4; ++r) {
    float r3 = rstd[r] * rstd[r] * rstd[r];
    gvar[r] = -0.5f * s3[r] * r3;
    gmu[r] = -s4[r] * rstd[r] + gvar[r] * (-2.0f * s5[r]) * 0.015625f;
  }
  // gZ -> LDS transposed [e][m], hi/lo bf16
#pragma unroll
  for (int t = 0; t < 4; ++t) {
    u16 hb[4], lb_[4];
#pragma unroll
    for (int r = 0; r < 4; ++r) {
      float gz = gxn[t][r] * rstd[r] + gvar[r] * 2.0f * xc[t][r] * 0.015625f + gmu[r] * 0.015625f;
      f2hl(gz, hb[r], lb_[r]);
    }
    uint2 ph, pl;
    ph.x = hb[0] | ((u32)hb[1] << 16); ph.y = hb[2] | ((u32)hb[3] << 16);
    pl.x = lb_[0] | ((u32)lb_[1] << 16); pl.y = lb_[2] | ((u32)lb_[3] << 16);
    *(uint2*)(&gzH[wv][(t * 16 + fr) * 24 + qd * 4]) = ph;
    *(uint2*)(&gzL[wv][(t * 16 + fr) * 24 + qd * 4]) = pl;
  }
  // Attn -> LDS transposed At[n][m]
  *(f32x4*)(&At[wv][fr * 20 + qd * 4]) = Atn;

  // Combined A = em[m]*(1 + tril(Attn))[m][n] for n<=m  (covers tril1 + Attn terms)
  float em = ep[fr];
  short8 aH = s8zero(), aL = s8zero();
  if (qd < 2) {
#pragma unroll
    for (int j = 0; j < 8; ++j) {
      int nn = qd * 8 + j;
      float av = 0.0f;
      if (nn <= fr) av = em * (1.0f + At[wv][nn * 20 + fr]);
      u16 hb, lb_;
      f2hl(av, hb, lb_);
      aH[j] = (short)hb;
      aL[j] = (short)lb_;
    }
  }
  // Zb = Q@W + b - Acomb@gZ
  f32x4 Ob[4];
#pragma unroll
  for (int t = 0; t < 4; ++t) {
    f32x4 a = {0.f, 0.f, 0.f, 0.f};
#pragma unroll
    for (int s = 0; s < 2; ++s) {
      short8 wH = *(const short8*)(&WtH[(t * 16 + fr) * 72 + s * 32 + qd * 8]);
      short8 wL = *(const short8*)(&WtL[(t * 16 + fr) * 72 + s * 32 + qd * 8]);
      a = MFMA16(qH[s], wH, a);
      a = MFMA16(qL[s], wH, a);
      a = MFMA16(qH[s], wL, a);
    }
    short8 gH = s8zero(), gL = s8zero();
    if (qd < 2) {
      gH = *(const short8*)(&gzH[wv][(t * 16 + fr) * 24 + qd * 8]);
      gL = *(const short8*)(&gzL[wv][(t * 16 + fr) * 24 + qd * 8]);
    }
    f32x4 c = {0.f, 0.f, 0.f, 0.f};
    c = MFMA16(aH, gH, c);
    c = MFMA16(aL, gH, c);
    c = MFMA16(aH, gL, c);
    float bv = bsh[t * 16 + fr];
#pragma unroll
    for (int r = 0; r < 4; ++r) Ob[t][r] = a[r] - c[r] + bv;
  }
  // out = Q + LN(Zb)
#pragma unroll
  for (int r = 0; r < 4; ++r) {
    float a0 = Ob[0][r], a1 = Ob[1][r], a2 = Ob[2][r], a3 = Ob[3][r];
    s1[r] = a0 + a1 + a2 + a3;
    s2[r] = a0 * a0 + a1 * a1 + a2 * a2 + a3 * a3;
  }
#pragma unroll
  for (int off = 1; off <= 8; off <<= 1) {
#pragma unroll
    for (int r = 0; r < 4; ++r) {
      s1[r] += __shfl_xor(s1[r], off, 64);
      s2[r] += __shfl_xor(s2[r], off, 64);
    }
  }
#pragma unroll
  for (int r = 0; r < 4; ++r) {
    mu[r] = s1[r] * 0.015625f;
    float var = s2[r] * 0.015625f - mu[r] * mu[r];
    rstd[r] = rsqrtf(var + 1e-5f);
  }
#pragma unroll
  for (int t = 0; t < 4; ++t) {
#pragma unroll
    for (int r = 0; r < 4; ++r) {
      float ln = (Ob[t][r] - mu[r]) * rstd[r] * gw[t] + gb[t];
      float qv = Qp[(qd * 4 + r) * 64 + t * 16 + fr];
      yout[((size_t)wv * 2048 + n * 16 + qd * 4 + r) * 1024 + h * 64 + t * 16 + fr] = qv + ln;
    }
  }
}

// ---------- kernel 4: post-LN + gate -> zb (bf16) ----------
__global__ __launch_bounds__(256) void k_postln(
    const float* __restrict__ yf, const u16* __restrict__ gateb,
    const float* __restrict__ post_w, const float* __restrict__ post_b, u16* __restrict__ zb) {
  __shared__ float red[8];
  int row = blockIdx.x, tid = threadIdx.x;
  int lane = tid & 63, wid = tid >> 6;
  const float* yr = yf + (size_t)row * 1024;
  float4 v = *(const float4*)(yr + tid * 4);
  float s1 = v.x + v.y + v.z + v.w;
  float s2 = v.x * v.x + v.y * v.y + v.z * v.z + v.w * v.w;
  s1 = wsum64(s1);
  s2 = wsum64(s2);
  if (lane == 0) { red[wid] = s1; red[4 + wid] = s2; }
  __syncthreads();
  s1 = red[0] + red[1] + red[2] + red[3];
  s2 = red[4] + red[5] + red[6] + red[7];
  float mu = s1 * (1.0f / 1024.0f);
  float var = s2 * (1.0f / 1024.0f) - mu * mu;
  float rstd = rsqrtf(var + 1e-5f);
  float vals[4] = {v.x, v.y, v.z, v.w};
  u16 ov[4];
#pragma unroll
  for (int i = 0; i < 4; ++i) {
    int cc = tid * 4 + i;
    float yn = (vals[i] - mu) * rstd * post_w[cc] + post_b[cc];
    float gt = bf2f(gateb[(size_t)row * 1024 + cc]);
    ov[i] = f2bf(gt * yn);
  }
  ushort4 o;
  o.x = ov[0]; o.y = ov[1]; o.z = ov[2]; o.w = ov[3];
  *(ushort4*)(zb + (size_t)row * 1024 + tid * 4) = o;
}

// ---------- kernel 5: output GEMM ----------
__global__ __launch_bounds__(256) void k_gemm2(const u16* __restrict__ A, const u16* __restrict__ Bw,
                                               float* __restrict__ Out) {
  __shared__ __align__(16) u16 sA[128 * 40];
  __shared__ __align__(16) u16 sB[128 * 40];
  int bm = blockIdx.x & 63, bn = blockIdx.x >> 6;
  f32x4 acc[4][4];
  gemm_core(A, Bw, bm, bn, sA, sB, acc);
  int tid = threadIdx.x, lane = tid & 63, wid = tid >> 6;
  int fr = lane & 15, qd = lane >> 4;
  int wm = (wid & 1) * 64, wn = (wid >> 1) * 64;
#pragma unroll
  for (int i = 0; i < 4; ++i) {
    int gr0 = bm * 128 + wm + i * 16 + qd * 4;
#pragma unroll
    for (int j = 0; j < 4; ++j) {
      int gc = bn * 128 + wn + j * 16 + fr;
#pragma unroll
      for (int r = 0; r < 4; ++r) Out[(size_t)(gr0 + r) * 1024 + gc] = acc[i][j][r];
    }
  }
}

// ---------- workspace layout (bytes) ----------
#define OFF_XB    ((size_t)0)          // 8192*1024 bf16      = 16777216
#define OFF_WCAT  ((size_t)16777216)   // 4224*1024 bf16      =  8650752
#define OFF_WOB   ((size_t)25427968)   // 1024*1024 bf16      =  2097152
#define OFF_Q     ((size_t)27525120)   // 4*16*2048*64 f32    = 33554432
#define OFF_K     ((size_t)61079552)
#define OFF_V     ((size_t)94633984)
#define OFF_GATE  ((size_t)128188416)  // 8192*1024 bf16
#define OFF_ETA   ((size_t)144965632)  // 4*16*2048 f32
#define OFF_WSEQ  ((size_t)145489920)  // 16*128*64*64 f32
#define OFF_BSEQ  ((size_t)179044352)  // 16*128*64 f32
#define OFF_Y     ((size_t)179568640)  // 8192*1024 f32
#define OFF_ZB    ((size_t)213123072)  // 8192*1024 bf16  (end = 229900288)

extern "C" void kernel_launch(void* const* d_in, const int* in_sizes, int n_in,
                              void* d_out, int out_size, void* d_ws, size_t ws_size,
                              hipStream_t stream) {
  const float* x    = (const float*)d_in[0];
  const float* Wq   = (const float*)d_in[1];
  const float* Wk   = (const float*)d_in[2];
  const float* Wv   = (const float*)d_in[3];
  const float* Wini = (const float*)d_in[4];
  const float* bini = (const float*)d_in[5];
  const float* ttw  = (const float*)d_in[6];
  const float* ttb  = (const float*)d_in[7];
  const float* pw   = (const float*)d_in[8];
  const float* pb   = (const float*)d_in[9];
  const float* lrw  = (const float*)d_in[10];
  const float* lrb  = (const float*)d_in[11];
  const float* tio  = (const float*)d_in[12];
  const float* Wg   = (const float*)d_in[13];
  const float* Wo   = (const float*)d_in[14];
  (void)in_sizes; (void)n_in; (void)out_size; (void)ws_size;
  float* out = (float*)d_out;
  char* ws = (char*)d_ws;
  u16* xb    = (u16*)(ws + OFF_XB);
  u16* Wcat  = (u16*)(ws + OFF_WCAT);
  u16* Wob   = (u16*)(ws + OFF_WOB);
  float* Qf  = (float*)(ws + OFF_Q);
  float* Kf  = (float*)(ws + OFF_K);
  float* Vf  = (float*)(ws + OFF_V);
  u16* gateb = (u16*)(ws + OFF_GATE);
  float* eta = (float*)(ws + OFF_ETA);
  float* Wsq = (float*)(ws + OFF_WSEQ);
  float* bsq = (float*)(ws + OFF_BSEQ);
  float* yf  = (float*)(ws + OFF_Y);
  u16* zbuf  = (u16*)(ws + OFF_ZB);

  hipLaunchKernelGGL(k_cast, dim3(13440), dim3(256), 0, stream, x, Wq, Wk, Wv, Wg, lrw, Wo, xb, Wcat, Wob);
  hipLaunchKernelGGL(k_gemm1, dim3(64 * 33), dim3(256), 0, stream, xb, Wcat, Qf, Kf, Vf, gateb, eta, lrb, tio);
  hipLaunchKernelGGL(k_phaseA, dim3(16), dim3(256), 0, stream, Kf, Vf, eta, Wini, bini, ttw, ttb, Wsq, bsq);
  hipLaunchKernelGGL(k_phaseB, dim3(2048), dim3(256), 0, stream, Qf, Kf, Vf, eta, Wsq, bsq, ttw, ttb, yf);
  hipLaunchKernelGGL(k_postln, dim3(8192), dim3(256), 0, stream, yf, gateb, pw, pb, zbuf);
  hipLaunchKernelGGL(k_gemm2, dim3(64 * 8), dim3(256), 0, stream, zbuf, Wob, out);
}